// Round 3
// baseline (15002.864 us; speedup 1.0000x reference)
//
#include <hip/hip_runtime.h>
#include <cstdint>
#include <cstddef>

typedef unsigned short u16;
typedef __attribute__((ext_vector_type(8))) short bf16x8;
typedef __attribute__((ext_vector_type(4))) float f32x4;

#define DMODEL 1024
#define TLEN   1024
#define BATCH  4
#define NHEAD  16

__device__ __forceinline__ float bf2f(u16 u) {
  union { unsigned int i; float f; } x; x.i = ((unsigned int)u) << 16; return x.f;
}
__device__ __forceinline__ u16 f2bf(float f) {
  union { float f; unsigned int i; } x; x.f = f;
  unsigned int r = x.i + 0x7fffu + ((x.i >> 16) & 1u);
  return (u16)(r >> 16);
}
__device__ __forceinline__ void ld8bf(const u16* p, float* f) {
  uint4 u = *(const uint4*)p;
  f[0] = bf2f((u16)(u.x & 0xffff)); f[1] = bf2f((u16)(u.x >> 16));
  f[2] = bf2f((u16)(u.y & 0xffff)); f[3] = bf2f((u16)(u.y >> 16));
  f[4] = bf2f((u16)(u.z & 0xffff)); f[5] = bf2f((u16)(u.z >> 16));
  f[6] = bf2f((u16)(u.w & 0xffff)); f[7] = bf2f((u16)(u.w >> 16));
}
__device__ __forceinline__ void ld4bf(const u16* p, float* f) {
  uint2 u = *(const uint2*)p;
  f[0] = bf2f((u16)(u.x & 0xffff)); f[1] = bf2f((u16)(u.x >> 16));
  f[2] = bf2f((u16)(u.y & 0xffff)); f[3] = bf2f((u16)(u.y >> 16));
}
__device__ __forceinline__ float softplus_f(float x) {
  return (x > 20.f) ? x : log1pf(__expf(x));
}
__device__ __forceinline__ void async_ld16(const void* g, void* l) {
  __builtin_amdgcn_global_load_lds(
      (const __attribute__((address_space(1))) unsigned int*)g,
      (__attribute__((address_space(3))) unsigned int*)l, 16, 0, 0);
}

// ---------------- embedding (all-fp32 inputs) ----------------
__global__ void embed_kernel(const int* __restrict__ tokens, const int* __restrict__ cat,
    const float* __restrict__ numf, const float* __restrict__ timef, const int* __restrict__ task_ids,
    const float* __restrict__ E, const float* __restrict__ ce0, const float* __restrict__ ce1,
    const float* __restrict__ Wn, const float* __restrict__ bn, const float* __restrict__ Wtm,
    const float* __restrict__ btm, const float* __restrict__ taskemb, float* __restrict__ X)
{
  const int bt = blockIdx.x;
  const int b = bt >> 10, t = bt & 1023;
  const int tok = tokens[bt];
  const int c0 = cat[bt * 2 + 0], c1 = cat[bt * 2 + 1];
  const int tk = task_ids[b];
  float nf[4], tf[6];
#pragma unroll
  for (int i = 0; i < 4; ++i) nf[i] = numf[bt * 4 + i];
#pragma unroll
  for (int i = 0; i < 6; ++i) tf[i] = timef[bt * 6 + i];
  const int d0 = threadIdx.x * 4;
  float v[4];
  {
    float4 a = *(const float4*)(E + (size_t)tok * DMODEL + d0);
    float4 b2 = *(const float4*)(ce0 + (size_t)c0 * DMODEL + d0);
    float4 c2 = *(const float4*)(ce1 + (size_t)c1 * DMODEL + d0);
    float4 d2 = *(const float4*)(taskemb + (size_t)tk * DMODEL + d0);
    float4 e2 = *(const float4*)(bn + d0);
    float4 f2 = *(const float4*)(btm + d0);
    v[0] = a.x + b2.x + c2.x + d2.x + e2.x + f2.x;
    v[1] = a.y + b2.y + c2.y + d2.y + e2.y + f2.y;
    v[2] = a.z + b2.z + c2.z + d2.z + e2.z + f2.z;
    v[3] = a.w + b2.w + c2.w + d2.w + e2.w + f2.w;
  }
#pragma unroll
  for (int i = 0; i < 4; ++i) {
    float4 w = *(const float4*)(Wn + (size_t)i * DMODEL + d0);
    v[0] += nf[i] * w.x; v[1] += nf[i] * w.y; v[2] += nf[i] * w.z; v[3] += nf[i] * w.w;
  }
#pragma unroll
  for (int i = 0; i < 6; ++i) {
    float4 w = *(const float4*)(Wtm + (size_t)i * DMODEL + d0);
    v[0] += tf[i] * w.x; v[1] += tf[i] * w.y; v[2] += tf[i] * w.z; v[3] += tf[i] * w.w;
  }
#pragma unroll
  for (int j = 0; j < 4; ++j) {
    const int d = d0 + j;
    const int i2 = d >> 1;
    const float ang = (float)t * expf(-0.017988946f * (float)i2);  // ln(1e4)/512
    v[j] += (d & 1) ? cosf(ang) : sinf(ang);
  }
  *(float4*)(X + (size_t)bt * DMODEL + d0) = make_float4(v[0], v[1], v[2], v[3]);
}

// ---------------- layernorm: fp32 in -> bf16 out (fp32 gamma/beta) ----------------
__global__ void ln_kernel(const float* __restrict__ X, const float* __restrict__ g,
                          const float* __restrict__ be, u16* __restrict__ O)
{
  const int row = blockIdx.x * 4 + (threadIdx.x >> 6);
  const int lane = threadIdx.x & 63;
  const float* xr = X + (size_t)row * DMODEL;
  float v[16];
  float s = 0.f, s2 = 0.f;
#pragma unroll
  for (int i = 0; i < 4; ++i) {
    float4 t4 = *(const float4*)(xr + lane * 4 + i * 256);
    v[i*4+0] = t4.x; v[i*4+1] = t4.y; v[i*4+2] = t4.z; v[i*4+3] = t4.w;
    s  += t4.x + t4.y + t4.z + t4.w;
    s2 += t4.x*t4.x + t4.y*t4.y + t4.z*t4.z + t4.w*t4.w;
  }
#pragma unroll
  for (int off = 32; off > 0; off >>= 1) {
    s  += __shfl_xor(s, off, 64);
    s2 += __shfl_xor(s2, off, 64);
  }
  const float mean = s * (1.f / 1024.f);
  const float var  = s2 * (1.f / 1024.f) - mean * mean;
  const float rs   = rsqrtf(var + 1e-5f);
  u16* orow = O + (size_t)row * DMODEL;
#pragma unroll
  for (int i = 0; i < 4; ++i) {
    float4 gg = *(const float4*)(g + lane * 4 + i * 256);
    float4 bb = *(const float4*)(be + lane * 4 + i * 256);
    float r0 = (v[i*4+0] - mean) * rs * gg.x + bb.x;
    float r1 = (v[i*4+1] - mean) * rs * gg.y + bb.y;
    float r2 = (v[i*4+2] - mean) * rs * gg.z + bb.z;
    float r3 = (v[i*4+3] - mean) * rs * gg.w + bb.w;
    uint2 o2;
    o2.x = (unsigned)f2bf(r0) | ((unsigned)f2bf(r1) << 16);
    o2.y = (unsigned)f2bf(r2) | ((unsigned)f2bf(r3) << 16);
    *(uint2*)(orow + lane * 4 + i * 256) = o2;
  }
}

// ---------------- fused convert+transpose: fp32 (R x C, ldin) -> bf16 (C x R) ----------------
__global__ void transpose_f2b(const float* __restrict__ in, u16* __restrict__ out,
                              int R, int C, int ldin)
{
  __shared__ u16 tile[64][65];
  const int c0 = blockIdx.x * 64, r0 = blockIdx.y * 64;
  const int tx = threadIdx.x & 15, ty = threadIdx.x >> 4;
#pragma unroll
  for (int i = 0; i < 4; ++i) {
    const int r = ty + i * 16;
    float4 f = *(const float4*)(in + (size_t)(r0 + r) * ldin + c0 + tx * 4);
    tile[r][tx*4+0] = f2bf(f.x);
    tile[r][tx*4+1] = f2bf(f.y);
    tile[r][tx*4+2] = f2bf(f.z);
    tile[r][tx*4+3] = f2bf(f.w);
  }
  __syncthreads();
#pragma unroll
  for (int i = 0; i < 4; ++i) {
    const int rr = ty + i * 16;
    uint2 o;
    o.x = (unsigned)tile[tx*4+0][rr] | ((unsigned)tile[tx*4+1][rr] << 16);
    o.y = (unsigned)tile[tx*4+2][rr] | ((unsigned)tile[tx*4+3][rr] << 16);
    *(uint2*)(out + (size_t)(c0 + rr) * R + r0 + tx * 4) = o;
  }
}

// ---------------- GEMM: C(MxN) = A(MxK,bf16,lda) @ Bt(NxK,bf16)^T (+bias fp32 +resid +relu) ----------------
template<bool RESID, bool RELU, bool OUTBF>
__global__ void gemm_bt(const u16* __restrict__ A, const u16* __restrict__ Bt,
                        const float* __restrict__ bias, const float* __restrict__ resid,
                        void* __restrict__ outp, int M, int N, int K, int lda)
{
  __shared__ u16 As[128 * 32];
  __shared__ u16 Bs[128 * 32];
  const int tid = threadIdx.x;
  const int wave = tid >> 6, lane = tid & 63;
  const int m0 = blockIdx.y * 128, n0 = blockIdx.x * 128;
  const int wm = (wave >> 1) * 64, wn = (wave & 1) * 64;
  const int lrow = lane & 15, quad = lane >> 4;
  f32x4 acc[4][4] = {};
  for (int kt = 0; kt < K; kt += 32) {
    __syncthreads();
#pragma unroll
    for (int p = 0; p < 2; ++p) {
      const int idx = p * 256 + tid;
      const int r = idx >> 2, cc = (idx & 3) << 3;
      const int lofs = (p * 256 + wave * 64) << 3;   // wave-uniform LDS base (elements)
      async_ld16(A + (size_t)(m0 + r) * lda + kt + cc, As + lofs);
      async_ld16(Bt + (size_t)(n0 + r) * K + kt + cc, Bs + lofs);
    }
    __syncthreads();
    bf16x8 af[4], bfr[4];
#pragma unroll
    for (int i = 0; i < 4; ++i) {
      af[i]  = *(const bf16x8*)(As + (wm + i * 16 + lrow) * 32 + quad * 8);
      bfr[i] = *(const bf16x8*)(Bs + (wn + i * 16 + lrow) * 32 + quad * 8);
    }
#pragma unroll
    for (int i = 0; i < 4; ++i)
#pragma unroll
      for (int j = 0; j < 4; ++j)
        acc[i][j] = __builtin_amdgcn_mfma_f32_16x16x32_bf16(af[i], bfr[j], acc[i][j], 0, 0, 0);
  }
#pragma unroll
  for (int i = 0; i < 4; ++i) {
#pragma unroll
    for (int j = 0; j < 4; ++j) {
      const int col = n0 + wn + j * 16 + lrow;
      const float bv = bias ? bias[col] : 0.f;
#pragma unroll
      for (int r = 0; r < 4; ++r) {
        const int row = m0 + wm + i * 16 + quad * 4 + r;
        float vv = acc[i][j][r] + bv;
        if (RESID) vv += resid[(size_t)row * N + col];
        if (RELU)  vv = fmaxf(vv, 0.f);
        if (OUTBF) ((u16*)outp)[(size_t)row * N + col] = f2bf(vv);
        else       ((float*)outp)[(size_t)row * N + col] = vv;
      }
    }
  }
}

// ---------------- attention: 1 thread = 1 q-row; writes output IN PLACE over Q slice ----------------
__global__ void attn_kernel(u16* __restrict__ QKV, const int* __restrict__ amask)
{
  const int gid = blockIdx.x * 256 + threadIdx.x;
  const int q = gid & (TLEN - 1);
  const int h = (gid >> 10) & (NHEAD - 1);
  const int b = gid >> 14;
  u16* qrow = QKV + (size_t)(b * TLEN + q) * 3072 + h * 64;
  float qf[64];
#pragma unroll
  for (int c = 0; c < 8; ++c) ld8bf(qrow + c * 8, qf + c * 8);
  float o[64];
#pragma unroll
  for (int d = 0; d < 64; ++d) o[d] = 0.f;
  float mrun = -1e30f, lrun = 0.f;
  const u16* Kbase = QKV + (size_t)b * TLEN * 3072 + 1024 + h * 64;
  const u16* Vbase = Kbase + 1024;
  const int* am = amask + b * TLEN;
  for (int k = 0; k <= q; ++k) {
    if (am[k] == 0) continue;
    const u16* kr = Kbase + (size_t)k * 3072;
    float s = 0.f;
#pragma unroll
    for (int c = 0; c < 8; ++c) {
      float kf[8];
      ld8bf(kr + c * 8, kf);
#pragma unroll
      for (int j = 0; j < 8; ++j) s += qf[c * 8 + j] * kf[j];
    }
    s *= 0.125f;  // 1/sqrt(64)
    const float nm = fmaxf(mrun, s);
    const float alpha = __expf(mrun - nm);
    const float p = __expf(s - nm);
    lrun = lrun * alpha + p;
    const u16* vr = Vbase + (size_t)k * 3072;
#pragma unroll
    for (int c = 0; c < 8; ++c) {
      float vf[8];
      ld8bf(vr + c * 8, vf);
#pragma unroll
      for (int j = 0; j < 8; ++j) o[c * 8 + j] = o[c * 8 + j] * alpha + p * vf[j];
    }
    mrun = nm;
  }
  const float inv = (lrun > 0.f) ? 1.f / lrun : 0.f;
#pragma unroll
  for (int c = 0; c < 8; ++c) {
    uint4 u;
    u.x = (unsigned)f2bf(o[c*8+0]*inv) | ((unsigned)f2bf(o[c*8+1]*inv) << 16);
    u.y = (unsigned)f2bf(o[c*8+2]*inv) | ((unsigned)f2bf(o[c*8+3]*inv) << 16);
    u.z = (unsigned)f2bf(o[c*8+4]*inv) | ((unsigned)f2bf(o[c*8+5]*inv) << 16);
    u.w = (unsigned)f2bf(o[c*8+6]*inv) | ((unsigned)f2bf(o[c*8+7]*inv) << 16);
    *(uint4*)(qrow + c * 8) = u;   // in-place: own q-slice, never read by other threads
  }
}

// ---------------- fold heads: MT[c][d] (128x1024 bf16), biasC[128] fp32 ----------------
__global__ void foldM(const float* __restrict__ E, const float* __restrict__ Wnext,
                      const float* __restrict__ Wtimeh, const float* __restrict__ bnext,
                      const float* __restrict__ btimeh, const float* __restrict__ s_act,
                      const float* __restrict__ s_time, u16* __restrict__ MT, float* __restrict__ biasC)
{
  const int c = blockIdx.x;  // 0..127
  const float sa = softplus_f(s_act[0]);
  const float st = softplus_f(s_time[0]);
  const int d0 = threadIdx.x * 4;
#pragma unroll
  for (int j = 0; j < 4; ++j) {
    const int d = d0 + j;
    float v = 0.f;
    if (c < 64)      v = Wnext[(size_t)d * 64 + c] + sa * E[(size_t)(4 + c) * DMODEL + d];
    else if (c < 96) v = Wtimeh[(size_t)d * 32 + (c - 64)] + st * E[(size_t)(68 + c - 64) * DMODEL + d];
    MT[(size_t)c * DMODEL + d] = f2bf(v);
  }
  if (threadIdx.x == 0) {
    float bv = 0.f;
    if (c < 64) bv = bnext[c];
    else if (c < 96) bv = btimeh[c - 64];
    biasC[c] = bv;
  }
}

// ---------------- build G[b][c][d] = sum over matching k of h[b,k,d] (bf16 h) ----------------
__global__ void gbuild(const int* __restrict__ tokens, const u16* __restrict__ HB,
                       float* __restrict__ G, int* __restrict__ Gnz)
{
  const int b = blockIdx.x;
  __shared__ int cls[1024];
  for (int i = threadIdx.x; i < 96 * 1024; i += 256) G[(size_t)b * 96 * 1024 + i] = 0.f;
  for (int k = threadIdx.x; k < 1024; k += 256) {
    int c = -1;
    if (k > 0 && tokens[b * 1024 + k - 1] == 3) {
      const int tok = tokens[b * 1024 + k];
      if (tok >= 4 && tok < 68) c = tok - 4;
      else if (tok >= 68 && tok < 100) c = 64 + (tok - 68);
    }
    cls[k] = c;
  }
  if (threadIdx.x < 96) Gnz[b * 96 + threadIdx.x] = 0;
  __syncthreads();
  const int d0 = threadIdx.x * 4;
  for (int k = 1; k < 1024; ++k) {
    const int c = cls[k];
    if (c < 0) continue;
    if (threadIdx.x == 0) Gnz[b * 96 + c] = 1;
    float* gr = G + ((size_t)b * 96 + c) * 1024 + d0;
    float hv[4];
    ld4bf(HB + ((size_t)b * 1024 + k) * 1024 + d0, hv);
#pragma unroll
    for (int j = 0; j < 4; ++j) gr[j] += hv[j];
  }
}

// ---------------- final: out = OUT96 + sp(copy_scale)*qm*(h . G_c)/32, fp32 out ----------------
__global__ void final_kernel(const u16* __restrict__ HB, const float* __restrict__ OUT96,
                             const float* __restrict__ G, const int* __restrict__ Gnz,
                             const int* __restrict__ lossm, const float* __restrict__ s_ca,
                             const float* __restrict__ s_ct, float* __restrict__ out_act,
                             float* __restrict__ out_time)
{
  __shared__ float hs[1024];
  const int row = blockIdx.x;  // b*T + q
  const int b = row >> 10;
  const u16* hrow = HB + (size_t)row * 1024;
  {
    const int i = threadIdx.x;  // 0..127, 8 elems each
    float hv[8];
    ld8bf(hrow + i * 8, hv);
#pragma unroll
    for (int j = 0; j < 8; ++j) hs[i * 8 + j] = hv[j];
  }
  __syncthreads();
  const int c = threadIdx.x;
  if (c >= 96) return;
  float val = OUT96[(size_t)row * 128 + c];
  if (lossm[row] != 0 && Gnz[b * 96 + c] != 0) {
    const float4* gr = (const float4*)(G + ((size_t)b * 96 + c) * 1024);
    float dot = 0.f;
    for (int d4 = 0; d4 < 256; ++d4) {
      float4 gg = gr[d4];
      dot += hs[d4*4+0]*gg.x + hs[d4*4+1]*gg.y + hs[d4*4+2]*gg.z + hs[d4*4+3]*gg.w;
    }
    const float sc = (c < 64) ? softplus_f(s_ca[0]) : softplus_f(s_ct[0]);
    val += sc * dot * (1.f / 32.f);
  }
  if (c < 64) out_act[(size_t)row * 64 + c] = val;
  else        out_time[(size_t)row * 32 + (c - 64)] = val;
}

extern "C" void kernel_launch(void* const* d_in, const int* in_sizes, int n_in,
                              void* d_out, int out_size, void* d_ws, size_t ws_size,
                              hipStream_t stream)
{
  const int*   tokens = (const int*)d_in[0];
  const int*   cat    = (const int*)d_in[1];
  const float* numf   = (const float*)d_in[2];
  const float* timef  = (const float*)d_in[3];
  const int*   amask  = (const int*)d_in[4];
  const int*   lossm  = (const int*)d_in[5];
  const int*   task   = (const int*)d_in[6];
  const float* E      = (const float*)d_in[7];
  const float* ce0    = (const float*)d_in[8];
  const float* ce1    = (const float*)d_in[9];
  const float* Wn     = (const float*)d_in[10];
  const float* bn     = (const float*)d_in[11];
  const float* Wtm    = (const float*)d_in[12];
  const float* btm    = (const float*)d_in[13];
  const float* Wqkv   = (const float*)d_in[14];
  const float* bqkv   = (const float*)d_in[15];
  const float* Wo     = (const float*)d_in[16];
  const float* bo     = (const float*)d_in[17];
  const float* ln1g   = (const float*)d_in[18];
  const float* ln1b   = (const float*)d_in[19];
  const float* W1     = (const float*)d_in[20];
  const float* b1     = (const float*)d_in[21];
  const float* W2     = (const float*)d_in[22];
  const float* b2     = (const float*)d_in[23];
  const float* ln2g   = (const float*)d_in[24];
  const float* ln2b   = (const float*)d_in[25];
  const float* lnfg   = (const float*)d_in[26];
  const float* lnfb   = (const float*)d_in[27];
  const float* Wnext  = (const float*)d_in[28];
  const float* bnext  = (const float*)d_in[29];
  const float* Wtimeh = (const float*)d_in[30];
  const float* btimeh = (const float*)d_in[31];
  const float* taskemb= (const float*)d_in[32];
  const float* ts_act = (const float*)d_in[33];
  const float* ts_time= (const float*)d_in[34];
  const float* cs_act = (const float*)d_in[35];
  const float* cs_time= (const float*)d_in[36];

  float* out_act  = (float*)d_out;
  float* out_time = out_act + (size_t)BATCH * TLEN * 64;

  // ---- compact workspace: 56 MB total ----
  uint8_t* ws = (uint8_t*)d_ws;
  float* X   = (float*)(ws);                       // 16 MB fp32 residual
  u16*   XB  = (u16*)(ws + (16ull << 20));         // 8 MB bf16 LN out / h
  u16*   SCR = (u16*)(ws + (24ull << 20));         // 24 MB: QKV (24M) | FFN mid-half (16M)
  u16*   WT  = (u16*)(ws + (48ull << 20));         // 8 MB transposed bf16 weights (max 6 MB used)
  // head phase aliases dead SCR:
  u16*   MT    = (u16*)  (ws + (24ull << 20));                 // 256 KB
  float* BIASC = (float*)(ws + (24ull << 20) + (512ull << 10));// 512 B
  float* OUT96 = (float*)(ws + (25ull << 20));                 // 2 MB
  float* G     = (float*)(ws + (28ull << 20));                 // 1.5 MB
  int*   GNZ   = (int*)  (ws + (30ull << 20));                 // 1.5 KB

  embed_kernel<<<4096, 256, 0, stream>>>(tokens, cat, numf, timef, task, E, ce0, ce1,
                                         Wn, bn, Wtm, btm, taskemb, X);

  for (int l = 0; l < 4; ++l) {
    // --- attention block ---
    ln_kernel<<<1024, 256, 0, stream>>>(X, ln1g + l * 1024, ln1b + l * 1024, XB);
    transpose_f2b<<<dim3(48, 16), 256, 0, stream>>>(Wqkv + (size_t)l * 1024 * 3072, WT, 1024, 3072, 3072);
    gemm_bt<false, false, true><<<dim3(24, 32), 256, 0, stream>>>(XB, WT, bqkv + l * 3072, nullptr, SCR, 4096, 3072, 1024, 1024);
    attn_kernel<<<256, 256, 0, stream>>>(SCR, amask);
    transpose_f2b<<<dim3(16, 16), 256, 0, stream>>>(Wo + (size_t)l * 1024 * 1024, WT, 1024, 1024, 1024);
    gemm_bt<true, false, false><<<dim3(8, 32), 256, 0, stream>>>(SCR /*attn out in Q slice*/, WT, bo + l * 1024, X, X, 4096, 1024, 1024, 3072);
    // --- FFN block, split into two N=2048 halves to bound scratch at 16 MB ---
    ln_kernel<<<1024, 256, 0, stream>>>(X, ln2g + l * 1024, ln2b + l * 1024, XB);
    for (int nh = 0; nh < 2; ++nh) {
      transpose_f2b<<<dim3(32, 16), 256, 0, stream>>>(W1 + (size_t)l * 1024 * 4096 + nh * 2048, WT, 1024, 2048, 4096);
      gemm_bt<false, true, true><<<dim3(16, 32), 256, 0, stream>>>(XB, WT, b1 + l * 4096 + nh * 2048, nullptr, SCR, 4096, 2048, 1024, 1024);
      transpose_f2b<<<dim3(16, 32), 256, 0, stream>>>(W2 + ((size_t)l * 4096 + nh * 2048) * 1024, WT, 2048, 1024, 1024);
      gemm_bt<true, false, false><<<dim3(8, 32), 256, 0, stream>>>(SCR, WT, nh == 0 ? (b2 + l * 1024) : nullptr, X, X, 4096, 1024, 2048, 2048);
    }
  }

  ln_kernel<<<1024, 256, 0, stream>>>(X, lnfg, lnfb, XB);
  foldM<<<128, 256, 0, stream>>>(E, Wnext, Wtimeh, bnext, btimeh, ts_act, ts_time, MT, BIASC);
  gemm_bt<false, false, false><<<dim3(1, 32), 256, 0, stream>>>(XB, MT, BIASC, nullptr, OUT96, 4096, 128, 1024, 1024);
  gbuild<<<4, 256, 0, stream>>>(tokens, XB, G, GNZ);
  final_kernel<<<4096, 128, 0, stream>>>(XB, OUT96, G, GNZ, lossm, cs_act, cs_time, out_act, out_time);
}

// Round 4
// 1842.300 us; speedup vs baseline: 8.1436x; 8.1436x over previous
//
#include <hip/hip_runtime.h>
#include <cstdint>
#include <cstddef>

typedef unsigned short u16;
typedef __attribute__((ext_vector_type(8))) short bf16x8;
typedef __attribute__((ext_vector_type(4))) float f32x4;

#define DMODEL 1024
#define TLEN   1024
#define BATCH  4
#define NHEAD  16

__device__ __forceinline__ float bf2f(u16 u) {
  union { unsigned int i; float f; } x; x.i = ((unsigned int)u) << 16; return x.f;
}
__device__ __forceinline__ u16 f2bf(float f) {
  union { float f; unsigned int i; } x; x.f = f;
  unsigned int r = x.i + 0x7fffu + ((x.i >> 16) & 1u);
  return (u16)(r >> 16);
}
__device__ __forceinline__ void ld8bf(const u16* p, float* f) {
  uint4 u = *(const uint4*)p;
  f[0] = bf2f((u16)(u.x & 0xffff)); f[1] = bf2f((u16)(u.x >> 16));
  f[2] = bf2f((u16)(u.y & 0xffff)); f[3] = bf2f((u16)(u.y >> 16));
  f[4] = bf2f((u16)(u.z & 0xffff)); f[5] = bf2f((u16)(u.z >> 16));
  f[6] = bf2f((u16)(u.w & 0xffff)); f[7] = bf2f((u16)(u.w >> 16));
}
__device__ __forceinline__ void ld4bf(const u16* p, float* f) {
  uint2 u = *(const uint2*)p;
  f[0] = bf2f((u16)(u.x & 0xffff)); f[1] = bf2f((u16)(u.x >> 16));
  f[2] = bf2f((u16)(u.y & 0xffff)); f[3] = bf2f((u16)(u.y >> 16));
}
__device__ __forceinline__ float softplus_f(float x) {
  return (x > 20.f) ? x : log1pf(__expf(x));
}
__device__ __forceinline__ void async_ld16(const void* g, void* l) {
  __builtin_amdgcn_global_load_lds(
      (const __attribute__((address_space(1))) unsigned int*)g,
      (__attribute__((address_space(3))) unsigned int*)l, 16, 0, 0);
}

// ---------------- embedding (all-fp32 inputs) ----------------
__global__ void embed_kernel(const int* __restrict__ tokens, const int* __restrict__ cat,
    const float* __restrict__ numf, const float* __restrict__ timef, const int* __restrict__ task_ids,
    const float* __restrict__ E, const float* __restrict__ ce0, const float* __restrict__ ce1,
    const float* __restrict__ Wn, const float* __restrict__ bn, const float* __restrict__ Wtm,
    const float* __restrict__ btm, const float* __restrict__ taskemb, float* __restrict__ X)
{
  const int bt = blockIdx.x;
  const int b = bt >> 10, t = bt & 1023;
  const int tok = tokens[bt];
  const int c0 = cat[bt * 2 + 0], c1 = cat[bt * 2 + 1];
  const int tk = task_ids[b];
  float nf[4], tf[6];
#pragma unroll
  for (int i = 0; i < 4; ++i) nf[i] = numf[bt * 4 + i];
#pragma unroll
  for (int i = 0; i < 6; ++i) tf[i] = timef[bt * 6 + i];
  const int d0 = threadIdx.x * 4;
  float v[4];
  {
    float4 a = *(const float4*)(E + (size_t)tok * DMODEL + d0);
    float4 b2 = *(const float4*)(ce0 + (size_t)c0 * DMODEL + d0);
    float4 c2 = *(const float4*)(ce1 + (size_t)c1 * DMODEL + d0);
    float4 d2 = *(const float4*)(taskemb + (size_t)tk * DMODEL + d0);
    float4 e2 = *(const float4*)(bn + d0);
    float4 f2 = *(const float4*)(btm + d0);
    v[0] = a.x + b2.x + c2.x + d2.x + e2.x + f2.x;
    v[1] = a.y + b2.y + c2.y + d2.y + e2.y + f2.y;
    v[2] = a.z + b2.z + c2.z + d2.z + e2.z + f2.z;
    v[3] = a.w + b2.w + c2.w + d2.w + e2.w + f2.w;
  }
#pragma unroll
  for (int i = 0; i < 4; ++i) {
    float4 w = *(const float4*)(Wn + (size_t)i * DMODEL + d0);
    v[0] += nf[i] * w.x; v[1] += nf[i] * w.y; v[2] += nf[i] * w.z; v[3] += nf[i] * w.w;
  }
#pragma unroll
  for (int i = 0; i < 6; ++i) {
    float4 w = *(const float4*)(Wtm + (size_t)i * DMODEL + d0);
    v[0] += tf[i] * w.x; v[1] += tf[i] * w.y; v[2] += tf[i] * w.z; v[3] += tf[i] * w.w;
  }
#pragma unroll
  for (int j = 0; j < 4; ++j) {
    const int d = d0 + j;
    const int i2 = d >> 1;
    const float ang = (float)t * expf(-0.017988946f * (float)i2);  // ln(1e4)/512
    v[j] += (d & 1) ? cosf(ang) : sinf(ang);
  }
  *(float4*)(X + (size_t)bt * DMODEL + d0) = make_float4(v[0], v[1], v[2], v[3]);
}

// ---------------- layernorm: fp32 in -> bf16 out (fp32 gamma/beta) ----------------
__global__ void ln_kernel(const float* __restrict__ X, const float* __restrict__ g,
                          const float* __restrict__ be, u16* __restrict__ O)
{
  const int row = blockIdx.x * 4 + (threadIdx.x >> 6);
  const int lane = threadIdx.x & 63;
  const float* xr = X + (size_t)row * DMODEL;
  float v[16];
  float s = 0.f, s2 = 0.f;
#pragma unroll
  for (int i = 0; i < 4; ++i) {
    float4 t4 = *(const float4*)(xr + lane * 4 + i * 256);
    v[i*4+0] = t4.x; v[i*4+1] = t4.y; v[i*4+2] = t4.z; v[i*4+3] = t4.w;
    s  += t4.x + t4.y + t4.z + t4.w;
    s2 += t4.x*t4.x + t4.y*t4.y + t4.z*t4.z + t4.w*t4.w;
  }
#pragma unroll
  for (int off = 32; off > 0; off >>= 1) {
    s  += __shfl_xor(s, off, 64);
    s2 += __shfl_xor(s2, off, 64);
  }
  const float mean = s * (1.f / 1024.f);
  const float var  = s2 * (1.f / 1024.f) - mean * mean;
  const float rs   = rsqrtf(var + 1e-5f);
  u16* orow = O + (size_t)row * DMODEL;
#pragma unroll
  for (int i = 0; i < 4; ++i) {
    float4 gg = *(const float4*)(g + lane * 4 + i * 256);
    float4 bb = *(const float4*)(be + lane * 4 + i * 256);
    float r0 = (v[i*4+0] - mean) * rs * gg.x + bb.x;
    float r1 = (v[i*4+1] - mean) * rs * gg.y + bb.y;
    float r2 = (v[i*4+2] - mean) * rs * gg.z + bb.z;
    float r3 = (v[i*4+3] - mean) * rs * gg.w + bb.w;
    uint2 o2;
    o2.x = (unsigned)f2bf(r0) | ((unsigned)f2bf(r1) << 16);
    o2.y = (unsigned)f2bf(r2) | ((unsigned)f2bf(r3) << 16);
    *(uint2*)(orow + lane * 4 + i * 256) = o2;
  }
}

// ---------------- fused convert+transpose: fp32 (R x C, ldin) -> bf16 (C x R) ----------------
__global__ void transpose_f2b(const float* __restrict__ in, u16* __restrict__ out,
                              int R, int C, int ldin)
{
  __shared__ u16 tile[64][65];
  const int c0 = blockIdx.x * 64, r0 = blockIdx.y * 64;
  const int tx = threadIdx.x & 15, ty = threadIdx.x >> 4;
#pragma unroll
  for (int i = 0; i < 4; ++i) {
    const int r = ty + i * 16;
    float4 f = *(const float4*)(in + (size_t)(r0 + r) * ldin + c0 + tx * 4);
    tile[r][tx*4+0] = f2bf(f.x);
    tile[r][tx*4+1] = f2bf(f.y);
    tile[r][tx*4+2] = f2bf(f.z);
    tile[r][tx*4+3] = f2bf(f.w);
  }
  __syncthreads();
#pragma unroll
  for (int i = 0; i < 4; ++i) {
    const int rr = ty + i * 16;
    uint2 o;
    o.x = (unsigned)tile[tx*4+0][rr] | ((unsigned)tile[tx*4+1][rr] << 16);
    o.y = (unsigned)tile[tx*4+2][rr] | ((unsigned)tile[tx*4+3][rr] << 16);
    *(uint2*)(out + (size_t)(c0 + rr) * R + r0 + tx * 4) = o;
  }
}

// ---------------- GEMM: C(MxN) = A(MxK,bf16,lda) @ Bt(NxK,bf16)^T (+bias fp32 +resid +relu) ----------------
template<bool RESID, bool RELU, bool OUTBF>
__global__ void gemm_bt(const u16* __restrict__ A, const u16* __restrict__ Bt,
                        const float* __restrict__ bias, const float* __restrict__ resid,
                        void* __restrict__ outp, int M, int N, int K, int lda)
{
  __shared__ u16 As[128 * 32];
  __shared__ u16 Bs[128 * 32];
  const int tid = threadIdx.x;
  const int wave = tid >> 6, lane = tid & 63;
  const int m0 = blockIdx.y * 128, n0 = blockIdx.x * 128;
  const int wm = (wave >> 1) * 64, wn = (wave & 1) * 64;
  const int lrow = lane & 15, quad = lane >> 4;
  f32x4 acc[4][4] = {};
  for (int kt = 0; kt < K; kt += 32) {
    __syncthreads();
#pragma unroll
    for (int p = 0; p < 2; ++p) {
      const int idx = p * 256 + tid;
      const int r = idx >> 2, cc = (idx & 3) << 3;
      const int lofs = (p * 256 + wave * 64) << 3;   // wave-uniform LDS base (elements)
      async_ld16(A + (size_t)(m0 + r) * lda + kt + cc, As + lofs);
      async_ld16(Bt + (size_t)(n0 + r) * K + kt + cc, Bs + lofs);
    }
    __syncthreads();
    bf16x8 af[4], bfr[4];
#pragma unroll
    for (int i = 0; i < 4; ++i) {
      af[i]  = *(const bf16x8*)(As + (wm + i * 16 + lrow) * 32 + quad * 8);
      bfr[i] = *(const bf16x8*)(Bs + (wn + i * 16 + lrow) * 32 + quad * 8);
    }
#pragma unroll
    for (int i = 0; i < 4; ++i)
#pragma unroll
      for (int j = 0; j < 4; ++j)
        acc[i][j] = __builtin_amdgcn_mfma_f32_16x16x32_bf16(af[i], bfr[j], acc[i][j], 0, 0, 0);
  }
#pragma unroll
  for (int i = 0; i < 4; ++i) {
#pragma unroll
    for (int j = 0; j < 4; ++j) {
      const int col = n0 + wn + j * 16 + lrow;
      const float bv = bias ? bias[col] : 0.f;
#pragma unroll
      for (int r = 0; r < 4; ++r) {
        const int row = m0 + wm + i * 16 + quad * 4 + r;
        float vv = acc[i][j][r] + bv;
        if (RESID) vv += resid[(size_t)row * N + col];
        if (RELU)  vv = fmaxf(vv, 0.f);
        if (OUTBF) ((u16*)outp)[(size_t)row * N + col] = f2bf(vv);
        else       ((float*)outp)[(size_t)row * N + col] = vv;
      }
    }
  }
}

// ---------------- MFMA flash attention ----------------
// Block = (qb: 64 q rows, h, b), 4 waves; wave owns 16 q rows.
// K-frags: 16B vector loads direct from global. V-frags: 8xu16 gather direct from global.
// P: wave-private LDS round-trip (C-layout -> A-layout). Output written in place over Q slice.
__launch_bounds__(256, 4)
__global__ void attn_flash(u16* __restrict__ QKV, const int* __restrict__ amask)
{
  __shared__ u16 Pw[4][16 * 72];   // per-wave P tile, stride 72 (16B-aligned rows, low conflict)
  const int tid  = threadIdx.x;
  const int wave = tid >> 6, lane = tid & 63;
  const int l15  = lane & 15, quad = lane >> 4;
  const int qb = blockIdx.x, h = blockIdx.y, b = blockIdx.z;
  const int qbase = qb * 64 + wave * 16;

  u16* bq = QKV + (size_t)b * TLEN * 3072 + h * 64;   // Q slice base (head h)
  const u16* Kb = bq + 1024;
  const u16* Vb = bq + 2048;
  const int* am = amask + b * TLEN;

  // Q A-frags (row = qbase + l15, dh chunk c*32 + quad*8 .. +7)
  bf16x8 aq0 = *(const bf16x8*)(bq + (size_t)(qbase + l15) * 3072 + quad * 8);
  bf16x8 aq1 = *(const bf16x8*)(bq + (size_t)(qbase + l15) * 3072 + 32 + quad * 8);

  f32x4 o[4] = {};          // O accum, C-layout: col dh = n*16+l15, row q = quad*4+r
  float m[4], l[4];
#pragma unroll
  for (int r = 0; r < 4; ++r) { m[r] = -1e30f; l[r] = 0.f; }

  u16* myP = Pw[wave];

  for (int kb = 0; kb <= qb; ++kb) {
    const int kt = kb * 64;
    // ---- S = Q K^T (4 n-tiles of 16 keys) ----
    float p[4][4];   // [j][r]
#pragma unroll
    for (int j = 0; j < 4; ++j) {
      const u16* kr = Kb + (size_t)(kt + j * 16 + l15) * 3072;
      bf16x8 bk0 = *(const bf16x8*)(kr + quad * 8);
      bf16x8 bk1 = *(const bf16x8*)(kr + 32 + quad * 8);
      f32x4 sacc = {};
      sacc = __builtin_amdgcn_mfma_f32_16x16x32_bf16(aq0, bk0, sacc, 0, 0, 0);
      sacc = __builtin_amdgcn_mfma_f32_16x16x32_bf16(aq1, bk1, sacc, 0, 0, 0);
      const float negm = (am[kt + j * 16 + l15] == 0) ? -1e9f : 0.f;
#pragma unroll
      for (int r = 0; r < 4; ++r) p[j][r] = sacc[r] * 0.125f + negm;
    }
    // causal mask (diagonal tile only): local col j*16+l15 vs local row wave*16+quad*4+r
    if (kb == qb) {
#pragma unroll
      for (int j = 0; j < 4; ++j) {
        const int colL = j * 16 + l15;
#pragma unroll
        for (int r = 0; r < 4; ++r) {
          const int rowL = wave * 16 + quad * 4 + r;
          if (colL > rowL) p[j][r] = -1e30f;
        }
      }
    }
    // ---- online softmax ----
#pragma unroll
    for (int r = 0; r < 4; ++r) {
      float mm = fmaxf(fmaxf(p[0][r], p[1][r]), fmaxf(p[2][r], p[3][r]));
      mm = fmaxf(mm, __shfl_xor(mm, 1));
      mm = fmaxf(mm, __shfl_xor(mm, 2));
      mm = fmaxf(mm, __shfl_xor(mm, 4));
      mm = fmaxf(mm, __shfl_xor(mm, 8));
      const float nm = fmaxf(m[r], mm);
      const float al = __expf(m[r] - nm);
      m[r] = nm;
      float ls = 0.f;
#pragma unroll
      for (int j = 0; j < 4; ++j) { p[j][r] = __expf(p[j][r] - nm); ls += p[j][r]; }
      ls += __shfl_xor(ls, 1); ls += __shfl_xor(ls, 2);
      ls += __shfl_xor(ls, 4); ls += __shfl_xor(ls, 8);
      l[r] = l[r] * al + ls;
#pragma unroll
      for (int n = 0; n < 4; ++n) o[n][r] *= al;
    }
    // ---- P: C-layout -> LDS (row-major [q16][key72]) ----
#pragma unroll
    for (int j = 0; j < 4; ++j)
#pragma unroll
      for (int r = 0; r < 4; ++r)
        myP[(quad * 4 + r) * 72 + j * 16 + l15] = f2bf(p[j][r]);
    __asm__ volatile("s_waitcnt lgkmcnt(0)" ::: "memory");
    // ---- O += P V ----
    bf16x8 pa0 = *(const bf16x8*)(myP + l15 * 72 + quad * 8);
    bf16x8 pa1 = *(const bf16x8*)(myP + l15 * 72 + 32 + quad * 8);
#pragma unroll
    for (int n = 0; n < 4; ++n) {
      const u16* vcol = Vb + n * 16 + l15;
#pragma unroll
      for (int c = 0; c < 2; ++c) {
        bf16x8 bv;
        short* pv = (short*)&bv;
#pragma unroll
        for (int jj = 0; jj < 8; ++jj)
          pv[jj] = (short)vcol[(size_t)(kt + c * 32 + quad * 8 + jj) * 3072];
        o[n] = __builtin_amdgcn_mfma_f32_16x16x32_bf16(c == 0 ? pa0 : pa1, bv, o[n], 0, 0, 0);
      }
    }
  }
  // ---- normalize + write in place over Q slice ----
#pragma unroll
  for (int r = 0; r < 4; ++r) {
    const float inv = (l[r] > 0.f) ? 1.f / l[r] : 0.f;
    u16* po = bq + (size_t)(qbase + quad * 4 + r) * 3072;
#pragma unroll
    for (int n = 0; n < 4; ++n)
      po[n * 16 + l15] = f2bf(o[n][r] * inv);
  }
}

// ---------------- fold heads: MT[c][d] (128x1024 bf16), biasC[128] fp32 ----------------
__global__ void foldM(const float* __restrict__ E, const float* __restrict__ Wnext,
                      const float* __restrict__ Wtimeh, const float* __restrict__ bnext,
                      const float* __restrict__ btimeh, const float* __restrict__ s_act,
                      const float* __restrict__ s_time, u16* __restrict__ MT, float* __restrict__ biasC)
{
  const int c = blockIdx.x;  // 0..127
  const float sa = softplus_f(s_act[0]);
  const float st = softplus_f(s_time[0]);
  const int d0 = threadIdx.x * 4;
#pragma unroll
  for (int j = 0; j < 4; ++j) {
    const int d = d0 + j;
    float v = 0.f;
    if (c < 64)      v = Wnext[(size_t)d * 64 + c] + sa * E[(size_t)(4 + c) * DMODEL + d];
    else if (c < 96) v = Wtimeh[(size_t)d * 32 + (c - 64)] + st * E[(size_t)(68 + c - 64) * DMODEL + d];
    MT[(size_t)c * DMODEL + d] = f2bf(v);
  }
  if (threadIdx.x == 0) {
    float bv = 0.f;
    if (c < 64) bv = bnext[c];
    else if (c < 96) bv = btimeh[c - 64];
    biasC[c] = bv;
  }
}

// ---------------- build G[b][c][d] = sum over matching k of h[b,k,d] (bf16 h) ----------------
__global__ void gbuild(const int* __restrict__ tokens, const u16* __restrict__ HB,
                       float* __restrict__ G, int* __restrict__ Gnz)
{
  const int b = blockIdx.x;
  __shared__ int cls[1024];
  for (int i = threadIdx.x; i < 96 * 1024; i += 256) G[(size_t)b * 96 * 1024 + i] = 0.f;
  for (int k = threadIdx.x; k < 1024; k += 256) {
    int c = -1;
    if (k > 0 && tokens[b * 1024 + k - 1] == 3) {
      const int tok = tokens[b * 1024 + k];
      if (tok >= 4 && tok < 68) c = tok - 4;
      else if (tok >= 68 && tok < 100) c = 64 + (tok - 68);
    }
    cls[k] = c;
  }
  if (threadIdx.x < 96) Gnz[b * 96 + threadIdx.x] = 0;
  __syncthreads();
  const int d0 = threadIdx.x * 4;
  for (int k = 1; k < 1024; ++k) {
    const int c = cls[k];
    if (c < 0) continue;
    if (threadIdx.x == 0) Gnz[b * 96 + c] = 1;
    float* gr = G + ((size_t)b * 96 + c) * 1024 + d0;
    float hv[4];
    ld4bf(HB + ((size_t)b * 1024 + k) * 1024 + d0, hv);
#pragma unroll
    for (int j = 0; j < 4; ++j) gr[j] += hv[j];
  }
}

// ---------------- final: out = OUT96 + sp(copy_scale)*qm*(h . G_c)/32, fp32 out ----------------
__global__ void final_kernel(const u16* __restrict__ HB, const float* __restrict__ OUT96,
                             const float* __restrict__ G, const int* __restrict__ Gnz,
                             const int* __restrict__ lossm, const float* __restrict__ s_ca,
                             const float* __restrict__ s_ct, float* __restrict__ out_act,
                             float* __restrict__ out_time)
{
  __shared__ float hs[1024];
  const int row = blockIdx.x;  // b*T + q
  const int b = row >> 10;
  const u16* hrow = HB + (size_t)row * 1024;
  {
    const int i = threadIdx.x;  // 0..127, 8 elems each
    float hv[8];
    ld8bf(hrow + i * 8, hv);
#pragma unroll
    for (int j = 0; j < 8; ++j) hs[i * 8 + j] = hv[j];
  }
  __syncthreads();
  const int c = threadIdx.x;
  if (c >= 96) return;
  float val = OUT96[(size_t)row * 128 + c];
  if (lossm[row] != 0 && Gnz[b * 96 + c] != 0) {
    const float4* gr = (const float4*)(G + ((size_t)b * 96 + c) * 1024);
    float dot = 0.f;
    for (int d4 = 0; d4 < 256; ++d4) {
      float4 gg = gr[d4];
      dot += hs[d4*4+0]*gg.x + hs[d4*4+1]*gg.y + hs[d4*4+2]*gg.z + hs[d4*4+3]*gg.w;
    }
    const float sc = (c < 64) ? softplus_f(s_ca[0]) : softplus_f(s_ct[0]);
    val += sc * dot * (1.f / 32.f);
  }
  if (c < 64) out_act[(size_t)row * 64 + c] = val;
  else        out_time[(size_t)row * 32 + (c - 64)] = val;
}

extern "C" void kernel_launch(void* const* d_in, const int* in_sizes, int n_in,
                              void* d_out, int out_size, void* d_ws, size_t ws_size,
                              hipStream_t stream)
{
  const int*   tokens = (const int*)d_in[0];
  const int*   cat    = (const int*)d_in[1];
  const float* numf   = (const float*)d_in[2];
  const float* timef  = (const float*)d_in[3];
  const int*   amask  = (const int*)d_in[4];
  const int*   lossm  = (const int*)d_in[5];
  const int*   task   = (const int*)d_in[6];
  const float* E      = (const float*)d_in[7];
  const float* ce0    = (const float*)d_in[8];
  const float* ce1    = (const float*)d_in[9];
  const float* Wn     = (const float*)d_in[10];
  const float* bn     = (const float*)d_in[11];
  const float* Wtm    = (const float*)d_in[12];
  const float* btm    = (const float*)d_in[13];
  const float* Wqkv   = (const float*)d_in[14];
  const float* bqkv   = (const float*)d_in[15];
  const float* Wo     = (const float*)d_in[16];
  const float* bo     = (const float*)d_in[17];
  const float* ln1g   = (const float*)d_in[18];
  const float* ln1b   = (const float*)d_in[19];
  const float* W1     = (const float*)d_in[20];
  const float* b1     = (const float*)d_in[21];
  const float* W2     = (const float*)d_in[22];
  const float* b2     = (const float*)d_in[23];
  const float* ln2g   = (const float*)d_in[24];
  const float* ln2b   = (const float*)d_in[25];
  const float* lnfg   = (const float*)d_in[26];
  const float* lnfb   = (const float*)d_in[27];
  const float* Wnext  = (const float*)d_in[28];
  const float* bnext  = (const float*)d_in[29];
  const float* Wtimeh = (const float*)d_in[30];
  const float* btimeh = (const float*)d_in[31];
  const float* taskemb= (const float*)d_in[32];
  const float* ts_act = (const float*)d_in[33];
  const float* ts_time= (const float*)d_in[34];
  const float* cs_act = (const float*)d_in[35];
  const float* cs_time= (const float*)d_in[36];

  float* out_act  = (float*)d_out;
  float* out_time = out_act + (size_t)BATCH * TLEN * 64;

  // ---- compact workspace: 56 MB total ----
  uint8_t* ws = (uint8_t*)d_ws;
  float* X   = (float*)(ws);                       // 16 MB fp32 residual
  u16*   XB  = (u16*)(ws + (16ull << 20));         // 8 MB bf16 LN out / h
  u16*   SCR = (u16*)(ws + (24ull << 20));         // 24 MB: QKV (24M) | FFN mid-half (16M)
  u16*   WT  = (u16*)(ws + (48ull << 20));         // 8 MB transposed bf16 weights (max 6 MB used)
  // head phase aliases dead SCR:
  u16*   MT    = (u16*)  (ws + (24ull << 20));                 // 256 KB
  float* BIASC = (float*)(ws + (24ull << 20) + (512ull << 10));// 512 B
  float* OUT96 = (float*)(ws + (25ull << 20));                 // 2 MB
  float* G     = (float*)(ws + (28ull << 20));                 // 1.5 MB
  int*   GNZ   = (int*)  (ws + (30ull << 20));                 // 1.5 KB

  embed_kernel<<<4096, 256, 0, stream>>>(tokens, cat, numf, timef, task, E, ce0, ce1,
                                         Wn, bn, Wtm, btm, taskemb, X);

  for (int l = 0; l < 4; ++l) {
    // --- attention block ---
    ln_kernel<<<1024, 256, 0, stream>>>(X, ln1g + l * 1024, ln1b + l * 1024, XB);
    transpose_f2b<<<dim3(48, 16), 256, 0, stream>>>(Wqkv + (size_t)l * 1024 * 3072, WT, 1024, 3072, 3072);
    gemm_bt<false, false, true><<<dim3(24, 32), 256, 0, stream>>>(XB, WT, bqkv + l * 3072, nullptr, SCR, 4096, 3072, 1024, 1024);
    attn_flash<<<dim3(16, 16, 4), 256, 0, stream>>>(SCR, amask);
    transpose_f2b<<<dim3(16, 16), 256, 0, stream>>>(Wo + (size_t)l * 1024 * 1024, WT, 1024, 1024, 1024);
    gemm_bt<true, false, false><<<dim3(8, 32), 256, 0, stream>>>(SCR /*attn out in Q slice*/, WT, bo + l * 1024, X, X, 4096, 1024, 1024, 3072);
    // --- FFN block, split into two N=2048 halves to bound scratch at 16 MB ---
    ln_kernel<<<1024, 256, 0, stream>>>(X, ln2g + l * 1024, ln2b + l * 1024, XB);
    for (int nh = 0; nh < 2; ++nh) {
      transpose_f2b<<<dim3(32, 16), 256, 0, stream>>>(W1 + (size_t)l * 1024 * 4096 + nh * 2048, WT, 1024, 2048, 4096);
      gemm_bt<false, true, true><<<dim3(16, 32), 256, 0, stream>>>(XB, WT, b1 + l * 4096 + nh * 2048, nullptr, SCR, 4096, 2048, 1024, 1024);
      transpose_f2b<<<dim3(16, 32), 256, 0, stream>>>(W2 + ((size_t)l * 4096 + nh * 2048) * 1024, WT, 2048, 1024, 1024);
      gemm_bt<true, false, false><<<dim3(8, 32), 256, 0, stream>>>(SCR, WT, nh == 0 ? (b2 + l * 1024) : nullptr, X, X, 4096, 1024, 2048, 2048);
    }
  }

  ln_kernel<<<1024, 256, 0, stream>>>(X, lnfg, lnfb, XB);
  foldM<<<128, 256, 0, stream>>>(E, Wnext, Wtimeh, bnext, btimeh, ts_act, ts_time, MT, BIASC);
  gemm_bt<false, false, false><<<dim3(1, 32), 256, 0, stream>>>(XB, MT, BIASC, nullptr, OUT96, 4096, 128, 1024, 1024);
  gbuild<<<4, 256, 0, stream>>>(tokens, XB, G, GNZ);
  final_kernel<<<4096, 128, 0, stream>>>(XB, OUT96, G, GNZ, lossm, cs_act, cs_time, out_act, out_time);
}